// Round 6
// baseline (18.211 us; speedup 1.0000x reference)
//
#include <hip/hip_runtime.h>
#include <math.h>

#define NFEAT 10
#define DICT 10000
#define EXB 16          // examples per block (one 16-row MFMA tile)
#define PITCH 164       // f32 row pitch in LDS (164 % 32 = 4 -> 2-way max aliasing)

typedef __attribute__((ext_vector_type(8))) short bf16x8;
typedef __attribute__((ext_vector_type(4))) float f32x4;
typedef __attribute__((ext_vector_type(4))) unsigned u32x4;

__device__ inline unsigned short f2bf(float f) {
    unsigned u = __builtin_bit_cast(unsigned, f);
    u += 0x7FFFu + ((u >> 16) & 1u);          // round-to-nearest-even
    return (unsigned short)(u >> 16);
}
__device__ inline unsigned cvt2(float lo, float hi) {
    return (unsigned)f2bf(lo) | ((unsigned)f2bf(hi) << 16);   // packed 2x bf16
}

// One block = one 16-example tile, 4 waves splitting the work:
//   wave 0: acc over k=0..15  (plain)  + exact-f32 linear term
//   wave 1: acc over k=16..31 (plain)
//   wave 2: acc over k=0..15  (squared x, squared K)
//   wave 3: acc over k=16..31 (squared x, squared K)
__global__ __launch_bounds__(256, 4) void fm_fused(
    const int* __restrict__ inputs,
    const float* __restrict__ user_table,
    const float* __restrict__ item_table,
    const float* __restrict__ feat_tables,
    const float* __restrict__ wvec,
    const float* __restrict__ bb,
    const float* __restrict__ k_mat,
    float* __restrict__ out)
{
    __shared__ float x[EXB][PITCH];       // gathered features, f32
    __shared__ int   idxs[EXB * NFEAT];
    __shared__ float part[5][EXB];        // 4 quadratic partials + linear

    const int tid = threadIdx.x;
    const int blk = blockIdx.x;

    // ---- phase 0: indices (640 B coalesced) ----
    if (tid < EXB * NFEAT)
        idxs[tid] = inputs[blk * EXB * NFEAT + tid];
    __syncthreads();

    // ---- phase 1: cooperative gather, 640 float4 loads spread over 256 thr ----
    for (int i = tid; i < EXB * 40; i += 256) {
        int e  = i / 40;
        int r  = i - e * 40;          // float4 index in the 160-float row
        int f  = r >> 2;
        int j4 = r & 3;
        int id = idxs[e * NFEAT + f];
        const float* tbl = (f == 0) ? user_table
                         : (f == 1) ? item_table
                         : feat_tables + (size_t)(f - 2) * (DICT * 16);
        float4 v = *(const float4*)(tbl + (size_t)id * 16 + j4 * 4);
        *(float4*)&x[e][r * 4] = v;
    }
    __syncthreads();

    const int lane = tid & 63;
    const int wid  = tid >> 6;
    const int col  = lane & 15;       // example row (A) / k col (C)
    const int kg   = lane >> 4;       // 8-dim K-chunk group
    const int koff = (wid & 1) * 16;  // which k-half this wave owns
    const bool sq  = (wid >= 2);      // squared variant?

    // ---- B fragments from k_mat (20 KB, L1-resident after first touch) ----
    bf16x8 bfrag[5];
    #pragma unroll
    for (int c = 0; c < 5; ++c) {
        const int dbase = c * 32 + kg * 8;
        float f[8];
        #pragma unroll
        for (int j = 0; j < 8; ++j)
            f[j] = k_mat[(dbase + j) * 32 + koff + col];
        u32x4 p;
        #pragma unroll
        for (int j = 0; j < 4; ++j) {
            float lo = f[2*j], hi = f[2*j+1];
            if (sq) { lo *= lo; hi *= hi; }
            p[j] = cvt2(lo, hi);
        }
        bfrag[c] = __builtin_bit_cast(bf16x8, p);
    }

    // ---- A fragments from LDS + 5 MFMAs ----
    f32x4 acc = {0, 0, 0, 0};
    #pragma unroll
    for (int c = 0; c < 5; ++c) {
        const float* xs = &x[col][c * 32 + kg * 8];
        float4 v0 = *(const float4*)xs;
        float4 v1 = *(const float4*)(xs + 4);
        if (sq) {
            v0.x *= v0.x; v0.y *= v0.y; v0.z *= v0.z; v0.w *= v0.w;
            v1.x *= v1.x; v1.y *= v1.y; v1.z *= v1.z; v1.w *= v1.w;
        }
        u32x4 p;
        p[0] = cvt2(v0.x, v0.y); p[1] = cvt2(v0.z, v0.w);
        p[2] = cvt2(v1.x, v1.y); p[3] = cvt2(v1.z, v1.w);
        bf16x8 a = __builtin_bit_cast(bf16x8, p);
        acc = __builtin_amdgcn_mfma_f32_16x16x32_bf16(a, bfrag[c], acc, 0, 0, 0);
    }

    // ---- wave 0: exact-f32 linear term (x . w) ----
    if (wid == 0) {
        const int e_l = lane & 15;
        const int q   = lane >> 4;        // quarter of the 160 dims
        float lin = 0.f;
        #pragma unroll
        for (int d0 = 0; d0 < 40; d0 += 4) {
            int d = q * 40 + d0;
            float4 xv = *(const float4*)&x[e_l][d];
            float4 wv = *(const float4*)&wvec[d];
            lin = fmaf(xv.x, wv.x, lin); lin = fmaf(xv.y, wv.y, lin);
            lin = fmaf(xv.z, wv.z, lin); lin = fmaf(xv.w, wv.w, lin);
        }
        lin += __shfl_xor(lin, 16, 64);
        lin += __shfl_xor(lin, 32, 64);
        if (lane < 16) part[4][lane] = lin;
    }

    // ---- per-wave reduction over its 16 k-cols; C row = kg*4+r ----
    #pragma unroll
    for (int r = 0; r < 4; ++r) {
        float v = sq ? -acc[r] : acc[r] * acc[r];
        #pragma unroll
        for (int m = 1; m <= 8; m <<= 1)
            v += __shfl_xor(v, m, 64);
        if (col == 0) part[wid][kg * 4 + r] = v;
    }
    __syncthreads();

    // ---- combine + sigmoid ----
    if (tid < EXB) {
        float v = part[0][tid] + part[1][tid] + part[2][tid] + part[3][tid];
        float z = part[4][tid] + bb[0] + 0.5f * v;
        out[blk * EXB + tid] = 1.0f / (1.0f + __expf(-z));
    }
}

extern "C" void kernel_launch(void* const* d_in, const int* in_sizes, int n_in,
                              void* d_out, int out_size, void* d_ws, size_t ws_size,
                              hipStream_t stream) {
    const int*   inputs      = (const int*)  d_in[0];
    const float* user_table  = (const float*)d_in[1];
    const float* item_table  = (const float*)d_in[2];
    const float* feat_tables = (const float*)d_in[3];
    const float* w           = (const float*)d_in[4];
    const float* b           = (const float*)d_in[5];
    const float* k_mat       = (const float*)d_in[6];
    float* out = (float*)d_out;

    int nblocks = out_size / EXB;   // 16384 / 16 = 1024
    fm_fused<<<nblocks, 256, 0, stream>>>(inputs, user_table, item_table,
                                          feat_tables, w, b, k_mat, out);
}

// Round 7
// 11.813 us; speedup vs baseline: 1.5416x; 1.5416x over previous
//
#include <hip/hip_runtime.h>
#include <hip/hip_bf16.h>
#include <math.h>

#define NFEAT 10
#define DICT 10000

typedef __attribute__((ext_vector_type(8))) short bf16x8;
typedef __attribute__((ext_vector_type(4))) float f32x4;
typedef __attribute__((ext_vector_type(4))) unsigned u32x4;

__device__ inline unsigned short f2bf(float f) {
    __hip_bfloat16 h = __float2bfloat16(f);   // RNE; compiler may pack pairs
    unsigned short s;
    __builtin_memcpy(&s, &h, sizeof(s));
    return s;
}
__device__ inline unsigned cvt2(float lo, float hi) {
    return (unsigned)f2bf(lo) | ((unsigned)f2bf(hi) << 16);   // 2x bf16 packed
}

// One block = 2 tiles x 2 waves. Per tile (16 examples):
//   even wave: acc0/acc1 = x @ K (both k-halves) + exact-f32 linear term
//   odd  wave: accT0/accT1 = x^2 @ K^2 (both k-halves) -> LDS handoff
// Single barrier; no x staging (each wave gathers its lanes' slices directly;
// partner wave's duplicate loads are same-CU L1 hits).
__global__ __launch_bounds__(256, 2) void fm_fused(
    const int* __restrict__ inputs,
    const float* __restrict__ user_table,
    const float* __restrict__ item_table,
    const float* __restrict__ feat_tables,
    const float* __restrict__ wvec,
    const float* __restrict__ bb,
    const float* __restrict__ k_mat,
    float* __restrict__ out)
{
    __shared__ float part_t[2][16];

    const int tid   = threadIdx.x;
    const int lane  = tid & 63;
    const int wid   = tid >> 6;          // 0..3
    const int tile  = wid >> 1;          // tile within block
    const bool sq   = (wid & 1) != 0;    // odd wave -> squared path
    const int gtile = blockIdx.x * 2 + tile;
    const int col   = lane & 15;         // example row (A) / k col (C)
    const int kg    = lane >> 4;         // 8-dim chunk group
    const int e     = gtile * 16 + col;
    const int fsel  = kg >> 1;           // even/odd feature
    const int hoff  = (kg & 1) * 8;      // half of the 16-float embedding

    // ---- index loads (5 per lane) ----
    int idx[5];
    #pragma unroll
    for (int c = 0; c < 5; ++c)
        idx[c] = inputs[e * NFEAT + 2 * c + fsel];

    // ---- gather x slices in f32 (independent, issued early) ----
    float4 u0[5], u1[5];
    #pragma unroll
    for (int c = 0; c < 5; ++c) {
        const float* tbl = (c == 0)
            ? (fsel ? item_table : user_table)
            : (feat_tables + (size_t)(2 * c + fsel - 2) * (DICT * 16));
        const float* src = tbl + (size_t)idx[c] * 16 + hoff;
        u0[c] = *(const float4*)src;
        u1[c] = *(const float4*)(src + 4);
    }

    // ---- B fragments from k_mat (L1-resident), squared on the odd wave ----
    bf16x8 b0[5], b1[5];
    #pragma unroll
    for (int c = 0; c < 5; ++c) {
        const int dbase = c * 32 + kg * 8;
        float f0[8], f1[8];
        #pragma unroll
        for (int j = 0; j < 8; ++j) {
            f0[j] = k_mat[(dbase + j) * 32 + col];
            f1[j] = k_mat[(dbase + j) * 32 + 16 + col];
        }
        if (sq) {
            #pragma unroll
            for (int j = 0; j < 8; ++j) { f0[j] *= f0[j]; f1[j] *= f1[j]; }
        }
        u32x4 p0, p1;
        #pragma unroll
        for (int j = 0; j < 4; ++j) {
            p0[j] = cvt2(f0[2*j], f0[2*j+1]);
            p1[j] = cvt2(f1[2*j], f1[2*j+1]);
        }
        b0[c] = __builtin_bit_cast(bf16x8, p0);
        b1[c] = __builtin_bit_cast(bf16x8, p1);
    }

    // ---- A fragments + 10 MFMAs (2 accumulator chains) ----
    f32x4 acc0 = {0,0,0,0};   // k = 0..15
    f32x4 acc1 = {0,0,0,0};   // k = 16..31
    #pragma unroll
    for (int c = 0; c < 5; ++c) {
        float4 v0 = u0[c], v1 = u1[c];
        if (sq) {
            v0.x *= v0.x; v0.y *= v0.y; v0.z *= v0.z; v0.w *= v0.w;
            v1.x *= v1.x; v1.y *= v1.y; v1.z *= v1.z; v1.w *= v1.w;
        }
        u32x4 p;
        p[0] = cvt2(v0.x, v0.y); p[1] = cvt2(v0.z, v0.w);
        p[2] = cvt2(v1.x, v1.y); p[3] = cvt2(v1.z, v1.w);
        bf16x8 a = __builtin_bit_cast(bf16x8, p);
        acc0 = __builtin_amdgcn_mfma_f32_16x16x32_bf16(a, b0[c], acc0, 0, 0, 0);
        acc1 = __builtin_amdgcn_mfma_f32_16x16x32_bf16(a, b1[c], acc1, 0, 0, 0);
    }

    // ---- even wave: exact-f32 linear term for its example (col) ----
    float lin = 0.f;
    if (!sq) {
        #pragma unroll
        for (int c = 0; c < 5; ++c) {
            const int dbase = c * 32 + kg * 8;
            float4 w0 = *(const float4*)&wvec[dbase];
            float4 w1 = *(const float4*)&wvec[dbase + 4];
            lin = fmaf(u0[c].x, w0.x, lin); lin = fmaf(u0[c].y, w0.y, lin);
            lin = fmaf(u0[c].z, w0.z, lin); lin = fmaf(u0[c].w, w0.w, lin);
            lin = fmaf(u1[c].x, w1.x, lin); lin = fmaf(u1[c].y, w1.y, lin);
            lin = fmaf(u1[c].z, w1.z, lin); lin = fmaf(u1[c].w, w1.w, lin);
        }
        lin += __shfl_xor(lin, 16, 64);
        lin += __shfl_xor(lin, 32, 64);   // all lanes: full lin[example=col]
    }

    // ---- per-wave k-reduction; C row = kg*4 + r ----
    float sv[4];
    #pragma unroll
    for (int r = 0; r < 4; ++r) {
        float v = sq ? (acc0[r] + acc1[r])                     // t partial
                     : (acc0[r]*acc0[r] + acc1[r]*acc1[r]);    // s^2 partial
        #pragma unroll
        for (int m = 1; m <= 8; m <<= 1)
            v += __shfl_xor(v, m, 64);                         // sum 16 cols
        sv[r] = v;
        if (sq && col == 0) part_t[tile][kg * 4 + r] = v;
    }
    __syncthreads();

    // ---- even wave: combine + sigmoid + store ----
    if (!sq) {
        const float bval = bb[0];
        #pragma unroll
        for (int r = 0; r < 4; ++r) {
            float lm = __shfl(lin, kg * 4 + r, 64);
            if (col == 0) {
                float z = lm + bval + 0.5f * (sv[r] - part_t[tile][kg * 4 + r]);
                out[gtile * 16 + kg * 4 + r] = 1.0f / (1.0f + __expf(-z));
            }
        }
    }
}

extern "C" void kernel_launch(void* const* d_in, const int* in_sizes, int n_in,
                              void* d_out, int out_size, void* d_ws, size_t ws_size,
                              hipStream_t stream) {
    const int*   inputs      = (const int*)  d_in[0];
    const float* user_table  = (const float*)d_in[1];
    const float* item_table  = (const float*)d_in[2];
    const float* feat_tables = (const float*)d_in[3];
    const float* w           = (const float*)d_in[4];
    const float* b           = (const float*)d_in[5];
    const float* k_mat       = (const float*)d_in[6];
    float* out = (float*)d_out;

    int nblocks = out_size / 32;    // 16384 / (2 tiles * 16 examples) = 512
    fm_fused<<<nblocks, 256, 0, stream>>>(inputs, user_table, item_table,
                                          feat_tables, w, b, k_mat, out);
}